// Round 2
// baseline (734.039 us; speedup 1.0000x reference)
//
#include <hip/hip_runtime.h>

#define EPS_BN 1e-5f

typedef __attribute__((ext_vector_type(8))) short short8;   // 8 bf16 (4 VGPR)
typedef __attribute__((ext_vector_type(4))) float floatx4;  // MFMA C/D

__device__ __forceinline__ short f2bf(float f) {            // RNE f32->bf16
    unsigned u = __float_as_uint(f);
    u += 0x7FFF + ((u >> 16) & 1);
    return (short)(u >> 16);
}

// ===========================================================================
// R5: persistent-block gather + branchless clamp-loads.
//  - grid = 1024 blocks (4/CU), grid-stride over 128-output tiles; 32KB W
//    staged ONCE per block instead of once per tile (5470x before).
//  - j-loop is straight-line: always load x[max(v,0)] (empty lanes broadcast
//    row 0 = L1 hit), cndmask to zero, convert, MFMA. No per-j skip branch.
//  - duplicate-coord chain: rare per-j branch (expect-not-taken).
//  - BN stats accumulated in registers across tiles, one LDS reduce at end.
//  - apply_kernel grid 1024 -> 4096 (pure-BW pass needs more waves).
//
// ws layout (bytes):
//   [512, 1024)   a[64], b[64] (finalize out)
//   [1024, +32K)  packedW: [j][tile][lane][8] bf16
//   then          partials: [128][1024] f32
//   then          slot: num_out*8 int (memset 0xFF)
//   then          next: n_vox int
//   then          chainmask: num_out u32 (memset 0x00)
// ===========================================================================

// Fragment-order W pack: packed[((j*4+t)*64+l)*8+i] = bf16(W[j][(l>>4)*8+i][(l&15)+16t])
__global__ void pack_W(const float* __restrict__ W, short* __restrict__ packed)
{
    const int s = blockIdx.x * 256 + threadIdx.x;   // 8 blocks x 256 = 2048
    const int j = s >> 8, t = (s >> 6) & 3, l = s & 63;
    const int k0 = (l >> 4) * 8, c = (l & 15) + 16 * t;
    short8 v;
#pragma unroll
    for (int i = 0; i < 8; ++i)
        v[i] = f2bf(W[(j * 32 + k0 + i) * 64 + c]);
    ((short8*)packed)[s] = v;
}

__global__ void scatter_slots(const int* __restrict__ out_idx,
                              const int* __restrict__ k_idx,
                              int* __restrict__ slot, int* __restrict__ next,
                              unsigned* __restrict__ chainmask, int n)
{
    int i = blockIdx.x * 256 + threadIdx.x;
    if (i < n) {
        const int o = out_idx[i];
        const int k = k_idx[i];
        int old = atomicExch(&slot[(size_t)o * 8 + k], i);
        next[i] = old;                       // chain walk needs -1 terminator
        if (old >= 0) atomicOr(&chainmask[o], 1u << k);   // rare (~2%)
    }
}

// ---------------------------------------------------------------------------
// MFMA gather: persistent blocks of 8 waves; each wave does 16 outputs/tile.
// ---------------------------------------------------------------------------
__global__ __launch_bounds__(512, 8) void gather_mfma(
    const float* __restrict__ x, const short* __restrict__ packedW,
    const int* __restrict__ slot, const int* __restrict__ next_arr,
    const unsigned* __restrict__ chainmask,
    float* __restrict__ out, float* __restrict__ partials,
    int num_out, int ntiles)
{
    __shared__ short sW[16384];          // 32 KB: [j][tile][lane][8]
    __shared__ float s_stat[128];

    const int tid = threadIdx.x;
    if (tid < 128) s_stat[tid] = 0.f;
    for (int i = tid; i < 2048; i += 512)
        ((short8*)sW)[i] = ((const short8*)packedW)[i];
    __syncthreads();

    const int wave = tid >> 6, lane = tid & 63;
    const int quad = lane >> 4, row = lane & 15;
    const short8* bw = (const short8*)sW;
    const float4* xq = (const float4*)x + quad * 2;   // row v -> xq + v*8

    float statS[4] = {0.f, 0.f, 0.f, 0.f};
    float statQ[4] = {0.f, 0.f, 0.f, 0.f};

    for (int tile = blockIdx.x; tile < ntiles; tile += gridDim.x) {
        const int obase = tile * 128 + wave * 16;
        const int o = obase + row;
        const bool valid_o = (o < num_out);

        int4 sl0 = make_int4(-1, -1, -1, -1), sl1 = sl0;
        unsigned cm = 0u;
        if (valid_o) {
            const int4* sp = (const int4*)(slot + (size_t)o * 8);
            sl0 = sp[0]; sl1 = sp[1];
            cm = chainmask[o];
        }
        const int sl[8] = {sl0.x, sl0.y, sl0.z, sl0.w, sl1.x, sl1.y, sl1.z, sl1.w};

        floatx4 acc[4] = {{0,0,0,0},{0,0,0,0},{0,0,0,0},{0,0,0,0}};

#pragma unroll
        for (int j = 0; j < 8; ++j) {
            const int v = sl[j];
            const float4* xp = xq + (size_t)(v < 0 ? 0 : v) * 8;
            float4 xa = xp[0], xb = xp[1];
            if (v < 0) {                     // cndmask, no branch
                xa = make_float4(0.f, 0.f, 0.f, 0.f);
                xb = make_float4(0.f, 0.f, 0.f, 0.f);
            }
            if (__builtin_expect(__any((cm >> j) & 1u), 0)) {   // rare dup chain
                int w = (v >= 0 && ((cm >> j) & 1u)) ? next_arr[v] : -1;
                while (__any(w >= 0)) {
                    if (w >= 0) {
                        const float4* xp2 = xq + (size_t)w * 8;
                        float4 ya = xp2[0], yb = xp2[1];
                        xa.x += ya.x; xa.y += ya.y; xa.z += ya.z; xa.w += ya.w;
                        xb.x += yb.x; xb.y += yb.y; xb.z += yb.z; xb.w += yb.w;
                        w = next_arr[w];
                    }
                }
            }
            short8 afrag;
            afrag[0] = f2bf(xa.x); afrag[1] = f2bf(xa.y);
            afrag[2] = f2bf(xa.z); afrag[3] = f2bf(xa.w);
            afrag[4] = f2bf(xb.x); afrag[5] = f2bf(xb.y);
            afrag[6] = f2bf(xb.z); afrag[7] = f2bf(xb.w);

            const int jb = j * 256;
#pragma unroll
            for (int t = 0; t < 4; ++t) {
                const short8 bfrag = bw[jb + t * 64 + lane];
                acc[t] = __builtin_amdgcn_mfma_f32_16x16x32_bf16(afrag, bfrag, acc[t], 0, 0, 0);
            }
        }

        // Epilogue: C layout col=lane&15, row=quad*4+reg. Store + reg stats.
#pragma unroll
        for (int t = 0; t < 4; ++t) {
            const int c = (lane & 15) + 16 * t;
#pragma unroll
            for (int r = 0; r < 4; ++r) {
                const int oc = obase + quad * 4 + r;
                const float val = acc[t][r];
                if (oc < num_out) {
                    out[(size_t)oc * 64 + c] = val;
                    statS[t] += val;
                    statQ[t] += val * val;
                }
            }
        }
    }

    // Final stats reduce (once per block)
#pragma unroll
    for (int t = 0; t < 4; ++t) {
        float sum = statS[t], sq = statQ[t];
        sum += __shfl_xor(sum, 16, 64); sum += __shfl_xor(sum, 32, 64);
        sq  += __shfl_xor(sq, 16, 64);  sq  += __shfl_xor(sq, 32, 64);
        if (quad == 0) {
            const int c = (lane & 15) + 16 * t;
            atomicAdd(&s_stat[c], sum);
            atomicAdd(&s_stat[64 + c], sq);
        }
    }
    __syncthreads();
    if (tid < 128) partials[(size_t)tid * gridDim.x + blockIdx.x] = s_stat[tid];
}

// One block per channel c: reduce partials, emit a[c], b[c].
// (conv bias cancels under BN: final = (acc-mean)*rsqrt(var)*gamma+beta)
__global__ __launch_bounds__(256) void reduce_finalize(
    const float* __restrict__ partials, const float* __restrict__ gamma,
    const float* __restrict__ beta, float* __restrict__ ws_ab,
    int nb, float inv_n)
{
    __shared__ float r1[256], r2[256];
    const int c = blockIdx.x, t = threadIdx.x;
    float s1 = 0.f, s2 = 0.f;
    for (int i = t; i < nb; i += 256) {
        s1 += partials[(size_t)c * nb + i];
        s2 += partials[(size_t)(c + 64) * nb + i];
    }
    r1[t] = s1; r2[t] = s2;
    __syncthreads();
    for (int d = 128; d > 0; d >>= 1) {
        if (t < d) { r1[t] += r1[t + d]; r2[t] += r2[t + d]; }
        __syncthreads();
    }
    if (t == 0) {
        const float mean = r1[0] * inv_n;
        const float var = r2[0] * inv_n - mean * mean;
        const float a = gamma[c] * rsqrtf(var + EPS_BN);
        ws_ab[c] = a;                        // a[64]
        ws_ab[64 + c] = beta[c] - mean * a;  // b[64]
    }
}

__global__ __launch_bounds__(256) void apply_kernel(
    float* __restrict__ out, const float* __restrict__ ws_ab, int n4)
{
    const int tid = blockIdx.x * 256 + threadIdx.x;
    const int stride = gridDim.x * 256;          // multiple of 16 -> cg fixed
    const int cg = tid & 15;
    const float4 a = ((const float4*)ws_ab)[cg];
    const float4 b = ((const float4*)(ws_ab + 64))[cg];
    float4* o4 = (float4*)out;
    for (int i = tid; i < n4; i += stride) {
        float4 v = o4[i];
        v.x = fmaxf(fmaf(v.x, a.x, b.x), 0.f);
        v.y = fmaxf(fmaf(v.y, a.y, b.y), 0.f);
        v.z = fmaxf(fmaf(v.z, a.z, b.z), 0.f);
        v.w = fmaxf(fmaf(v.w, a.w, b.w), 0.f);
        o4[i] = v;
    }
}

extern "C" void kernel_launch(void* const* d_in, const int* in_sizes, int n_in,
                              void* d_out, int out_size, void* d_ws, size_t ws_size,
                              hipStream_t stream)
{
    const float* x     = (const float*)d_in[0];
    const float* W     = (const float*)d_in[1];
    // d_in[2] = bias: cancels under BN, unused.
    const float* gamma = (const float*)d_in[3];
    const float* beta  = (const float*)d_in[4];
    const int* k_idx   = (const int*)d_in[5];
    const int* out_idx = (const int*)d_in[6];

    const int n_vox   = in_sizes[5];
    const int num_out = out_size / 64;
    const int ntiles  = (num_out + 127) / 128;   // 128 outputs per tile
    const int nbg     = (ntiles < 1024) ? ntiles : 1024;   // persistent blocks
    float* out = (float*)d_out;

    char* p = (char*)d_ws;
    float* ws_ab    = (float*)(p + 512);                 // a[64], b[64]
    short* packedW  = (short*)(p + 1024);                // 32 KB
    float* partials = (float*)(p + 1024 + 32768);        // 128*1024 f32 max
    char*  p2       = p + 1024 + 32768 + (size_t)128 * 1024 * 4;
    int*   slot     = (int*)p2;                          // num_out*8
    int*   next     = slot + (size_t)num_out * 8;        // n_vox
    unsigned* chainmask = (unsigned*)(next + n_vox);     // num_out

    hipMemsetAsync(slot, 0xFF, (size_t)num_out * 8 * sizeof(int), stream);
    hipMemsetAsync(chainmask, 0, (size_t)num_out * sizeof(unsigned), stream);

    pack_W        <<<8, 256, 0, stream>>>(W, packedW);
    scatter_slots <<<(n_vox + 255) / 256, 256, 0, stream>>>(out_idx, k_idx, slot, next, chainmask, n_vox);
    gather_mfma   <<<nbg, 512, 0, stream>>>(x, packedW, slot, next, chainmask, out, partials, num_out, ntiles);
    reduce_finalize<<<64, 256, 0, stream>>>(partials, gamma, beta, ws_ab, nbg, 1.0f / (float)num_out);
    apply_kernel  <<<4096, 256, 0, stream>>>(out, ws_ab, out_size / 4);
}

// Round 3
// 428.187 us; speedup vs baseline: 1.7143x; 1.7143x over previous
//
#include <hip/hip_runtime.h>

#define EPS_BN 1e-5f

typedef __attribute__((ext_vector_type(8))) short short8;   // 8 bf16 (4 VGPR)
typedef __attribute__((ext_vector_type(4))) float floatx4;  // MFMA C/D

__device__ __forceinline__ short f2bf(float f) {            // RNE f32->bf16
    unsigned u = __float_as_uint(f);
    u += 0x7FFF + ((u >> 16) & 1);
    return (short)(u >> 16);
}

// ===========================================================================
// R6: R4 structure (one 128-output tile per block, exec-masked loads --
// proven 64MB fetch) + MLP: j-loop split into halves of 4:
//   Phase A: 4 guarded x-row loads -> registers (4 loads in flight/wave)
//   Phase B: one rare chain-fixup branch per half
//   Phase C: convert + 16 MFMA
// R5's broadcast-clamp loads caused a 680MB fetch blowup (non-deduped
// row-0 traffic) -- reverted. launch_bounds(512,4) for the +32 VGPR.
//
// ws layout (bytes):
//   [512, 1024)   a[64], b[64] (finalize out)
//   [1024, +32K)  packedW: [j][tile][lane][8] bf16
//   then          partials: [128][nb] f32
//   then          slot: num_out*8 int (memset 0xFF)
//   then          next: n_vox int
//   then          chainmask: num_out u32 (memset 0x00)
// ===========================================================================

// Fragment-order W pack: packed[((j*4+t)*64+l)*8+i] = bf16(W[j][(l>>4)*8+i][(l&15)+16t])
__global__ void pack_W(const float* __restrict__ W, short* __restrict__ packed)
{
    const int s = blockIdx.x * 256 + threadIdx.x;   // 8 blocks x 256 = 2048
    const int j = s >> 8, t = (s >> 6) & 3, l = s & 63;
    const int k0 = (l >> 4) * 8, c = (l & 15) + 16 * t;
    short8 v;
#pragma unroll
    for (int i = 0; i < 8; ++i)
        v[i] = f2bf(W[(j * 32 + k0 + i) * 64 + c]);
    ((short8*)packed)[s] = v;
}

__global__ void scatter_slots(const int* __restrict__ out_idx,
                              const int* __restrict__ k_idx,
                              int* __restrict__ slot, int* __restrict__ next,
                              unsigned* __restrict__ chainmask, int n)
{
    int i = blockIdx.x * 256 + threadIdx.x;
    if (i < n) {
        const int o = out_idx[i];
        const int k = k_idx[i];
        int old = atomicExch(&slot[(size_t)o * 8 + k], i);
        next[i] = old;                       // chain walk needs -1 terminator
        if (old >= 0) atomicOr(&chainmask[o], 1u << k);   // rare (~2%)
    }
}

// ---------------------------------------------------------------------------
// MFMA gather: block = 8 waves x 16 outputs = 128 outputs.
// ---------------------------------------------------------------------------
__global__ __launch_bounds__(512, 4) void gather_mfma(
    const float* __restrict__ x, const short* __restrict__ packedW,
    const int* __restrict__ slot, const int* __restrict__ next_arr,
    const unsigned* __restrict__ chainmask,
    float* __restrict__ out, float* __restrict__ partials,
    int num_out, int nb)
{
    __shared__ short sW[16384];          // 32 KB: [j][tile][lane][8]
    __shared__ float s_stat[128];

    const int tid = threadIdx.x;
    if (tid < 128) s_stat[tid] = 0.f;
    for (int i = tid; i < 2048; i += 512)
        ((short8*)sW)[i] = ((const short8*)packedW)[i];
    __syncthreads();

    const int wave = tid >> 6, lane = tid & 63;
    const int quad = lane >> 4, row = lane & 15;
    const int obase = blockIdx.x * 128 + wave * 16;
    const int o = obase + row;
    const bool valid_o = (o < num_out);

    // 8 slots + chainmask for this output row
    int4 sl0 = make_int4(-1, -1, -1, -1), sl1 = sl0;
    unsigned cm = 0u;
    if (valid_o) {
        const int4* sp = (const int4*)(slot + (size_t)o * 8);
        sl0 = sp[0]; sl1 = sp[1];
        cm = chainmask[o];
    }
    const int s0 = sl0.x, s1 = sl0.y, s2 = sl0.z, s3 = sl0.w;
    const int s4 = sl1.x, s5 = sl1.y, s6 = sl1.z, s7 = sl1.w;

    floatx4 acc[4] = {{0,0,0,0},{0,0,0,0},{0,0,0,0},{0,0,0,0}};
    const short8* bw = (const short8*)sW;

#pragma unroll
    for (int h = 0; h < 2; ++h) {
        float4 XA[4], XB[4];
        // ---- Phase A: 4 guarded loads in flight ----
#pragma unroll
        for (int jj = 0; jj < 4; ++jj) {
            const int j = h * 4 + jj;
            const int v = (j == 0) ? s0 : (j == 1) ? s1 : (j == 2) ? s2 : (j == 3) ? s3
                        : (j == 4) ? s4 : (j == 5) ? s5 : (j == 6) ? s6 : s7;
            XA[jj] = make_float4(0.f, 0.f, 0.f, 0.f);
            XB[jj] = make_float4(0.f, 0.f, 0.f, 0.f);
            if (v >= 0) {                            // exec-masked (empty = free)
                const float4* xp = (const float4*)(x + (size_t)v * 32) + quad * 2;
                XA[jj] = xp[0];
                XB[jj] = xp[1];
            }
        }
        // ---- Phase B: rare duplicate-coord chains (once per half) ----
        const unsigned hm = (cm >> (h * 4)) & 0xFu;
        if (__builtin_expect(__any(hm != 0u), 0)) {
#pragma unroll
            for (int jj = 0; jj < 4; ++jj) {
                const int j = h * 4 + jj;
                const int v = (j == 0) ? s0 : (j == 1) ? s1 : (j == 2) ? s2 : (j == 3) ? s3
                            : (j == 4) ? s4 : (j == 5) ? s5 : (j == 6) ? s6 : s7;
                int w = (((cm >> j) & 1u) && v >= 0) ? next_arr[v] : -1;
                while (__any(w >= 0)) {
                    if (w >= 0) {
                        const float4* xp2 = (const float4*)(x + (size_t)w * 32) + quad * 2;
                        float4 ya = xp2[0], yb = xp2[1];
                        XA[jj].x += ya.x; XA[jj].y += ya.y; XA[jj].z += ya.z; XA[jj].w += ya.w;
                        XB[jj].x += yb.x; XB[jj].y += yb.y; XB[jj].z += yb.z; XB[jj].w += yb.w;
                        w = next_arr[w];
                    }
                }
            }
        }
        // ---- Phase C: convert + MFMA ----
#pragma unroll
        for (int jj = 0; jj < 4; ++jj) {
            const int j = h * 4 + jj;
            short8 afrag;
            afrag[0] = f2bf(XA[jj].x); afrag[1] = f2bf(XA[jj].y);
            afrag[2] = f2bf(XA[jj].z); afrag[3] = f2bf(XA[jj].w);
            afrag[4] = f2bf(XB[jj].x); afrag[5] = f2bf(XB[jj].y);
            afrag[6] = f2bf(XB[jj].z); afrag[7] = f2bf(XB[jj].w);
            const int jb = j * 256;
#pragma unroll
            for (int t = 0; t < 4; ++t) {
                const short8 bfrag = bw[jb + t * 64 + lane];
                acc[t] = __builtin_amdgcn_mfma_f32_16x16x32_bf16(afrag, bfrag, acc[t], 0, 0, 0);
            }
        }
    }

    // Epilogue: C layout col=lane&15, row=quad*4+reg. Store + fused stats.
#pragma unroll
    for (int t = 0; t < 4; ++t) {
        const int c = (lane & 15) + 16 * t;
        float sum = 0.f, sq = 0.f;
#pragma unroll
        for (int r = 0; r < 4; ++r) {
            const int oc = obase + quad * 4 + r;
            const float val = acc[t][r];
            if (oc < num_out) {
                out[(size_t)oc * 64 + c] = val;
                sum += val; sq += val * val;
            }
        }
        sum += __shfl_xor(sum, 16, 64); sum += __shfl_xor(sum, 32, 64);
        sq  += __shfl_xor(sq, 16, 64);  sq  += __shfl_xor(sq, 32, 64);
        if (quad == 0) {
            atomicAdd(&s_stat[c], sum);
            atomicAdd(&s_stat[64 + c], sq);
        }
    }
    __syncthreads();
    if (tid < 128) partials[(size_t)tid * nb + blockIdx.x] = s_stat[tid];
}

// One block per channel c: reduce partials, emit a[c], b[c].
// (conv bias cancels under BN: final = (acc-mean)*rsqrt(var)*gamma+beta)
__global__ __launch_bounds__(256) void reduce_finalize(
    const float* __restrict__ partials, const float* __restrict__ gamma,
    const float* __restrict__ beta, float* __restrict__ ws_ab,
    int nb, float inv_n)
{
    __shared__ float r1[256], r2[256];
    const int c = blockIdx.x, t = threadIdx.x;
    float s1 = 0.f, s2 = 0.f;
    for (int i = t; i < nb; i += 256) {
        s1 += partials[(size_t)c * nb + i];
        s2 += partials[(size_t)(c + 64) * nb + i];
    }
    r1[t] = s1; r2[t] = s2;
    __syncthreads();
    for (int d = 128; d > 0; d >>= 1) {
        if (t < d) { r1[t] += r1[t + d]; r2[t] += r2[t + d]; }
        __syncthreads();
    }
    if (t == 0) {
        const float mean = r1[0] * inv_n;
        const float var = r2[0] * inv_n - mean * mean;
        const float a = gamma[c] * rsqrtf(var + EPS_BN);
        ws_ab[c] = a;                        // a[64]
        ws_ab[64 + c] = beta[c] - mean * a;  // b[64]
    }
}

__global__ __launch_bounds__(256) void apply_kernel(
    float* __restrict__ out, const float* __restrict__ ws_ab, int n4)
{
    const int tid = blockIdx.x * 256 + threadIdx.x;
    const int stride = gridDim.x * 256;          // multiple of 16 -> cg fixed
    const int cg = tid & 15;
    const float4 a = ((const float4*)ws_ab)[cg];
    const float4 b = ((const float4*)(ws_ab + 64))[cg];
    float4* o4 = (float4*)out;
    for (int i = tid; i < n4; i += stride) {
        float4 v = o4[i];
        v.x = fmaxf(fmaf(v.x, a.x, b.x), 0.f);
        v.y = fmaxf(fmaf(v.y, a.y, b.y), 0.f);
        v.z = fmaxf(fmaf(v.z, a.z, b.z), 0.f);
        v.w = fmaxf(fmaf(v.w, a.w, b.w), 0.f);
        o4[i] = v;
    }
}

extern "C" void kernel_launch(void* const* d_in, const int* in_sizes, int n_in,
                              void* d_out, int out_size, void* d_ws, size_t ws_size,
                              hipStream_t stream)
{
    const float* x     = (const float*)d_in[0];
    const float* W     = (const float*)d_in[1];
    // d_in[2] = bias: cancels under BN, unused.
    const float* gamma = (const float*)d_in[3];
    const float* beta  = (const float*)d_in[4];
    const int* k_idx   = (const int*)d_in[5];
    const int* out_idx = (const int*)d_in[6];

    const int n_vox   = in_sizes[5];
    const int num_out = out_size / 64;
    const int nb      = (num_out + 127) / 128;   // gather blocks (128 outputs)
    float* out = (float*)d_out;

    char* p = (char*)d_ws;
    float* ws_ab    = (float*)(p + 512);                 // a[64], b[64]
    short* packedW  = (short*)(p + 1024);                // 32 KB
    float* partials = (float*)(p + 1024 + 32768);        // 128*nb f32
    char*  p2       = p + 1024 + 32768 + (size_t)128 * nb * 4;
    int*   slot     = (int*)p2;                          // num_out*8
    int*   next     = slot + (size_t)num_out * 8;        // n_vox
    unsigned* chainmask = (unsigned*)(next + n_vox);     // num_out

    hipMemsetAsync(slot, 0xFF, (size_t)num_out * 8 * sizeof(int), stream);
    hipMemsetAsync(chainmask, 0, (size_t)num_out * sizeof(unsigned), stream);

    pack_W        <<<8, 256, 0, stream>>>(W, packedW);
    scatter_slots <<<(n_vox + 255) / 256, 256, 0, stream>>>(out_idx, k_idx, slot, next, chainmask, n_vox);
    gather_mfma   <<<nb, 512, 0, stream>>>(x, packedW, slot, next, chainmask, out, partials, num_out, nb);
    reduce_finalize<<<64, 256, 0, stream>>>(partials, gamma, beta, ws_ab, nb, 1.0f / (float)num_out);
    apply_kernel  <<<4096, 256, 0, stream>>>(out, ws_ab, out_size / 4);
}

// Round 5
// 404.604 us; speedup vs baseline: 1.8142x; 1.0583x over previous
//
#include <hip/hip_runtime.h>

#define EPS_BN 1e-5f

typedef __attribute__((ext_vector_type(8))) short short8;   // 8 bf16 (4 VGPR)
typedef __attribute__((ext_vector_type(4))) float floatx4;  // MFMA C/D, nt-store

__device__ __forceinline__ short f2bf(float f) {            // RNE f32->bf16
    unsigned u = __float_as_uint(f);
    u += 0x7FFF + ((u >> 16) & 1);
    return (short)(u >> 16);
}

// ===========================================================================
// R7b: R7 with compile fix (nontemporal store needs clang ext_vector type,
// not HIP float4 class). Gather restored to R4-exact structure (proven
// 120us, 64MB fetch): one 128-output tile per block, 8 waves, per-j
// exec-masked loads with __any skip, launch_bounds(512,8). Changes vs R4:
//   - slot/chainmask loads hoisted ABOVE the LDS W-staging.
//   - pack_W folded into scatter kernel (blocks 0-7).
//   - chainmask inverted (init 0xFF, atomicAnd on collision) so slot +
//     chainmask share ONE contiguous 0xFF memset.  Dispatches: 5.
//   - apply uses nontemporal stores (out never re-read; keep L3 for y).
// R5 lesson: NEVER broadcast-clamp loads (row-0 traffic blowup).
// R6 lesson: keep launch_bounds min-waves at 8 (4 halved occupancy).
//
// ws layout (bytes):
//   [512, 1024)   a[64], b[64] (finalize out)
//   [1024, +32K)  packedW: [j][tile][lane][8] bf16
//   then          partials: [128][nb] f32
//   then          slot: num_out*8 int   \ one 0xFF memset
//   then          cm_inv: num_out u32   /  (contiguous)
//   then          next: n_vox int
// ===========================================================================

// Fused scatter + W-pack. Blocks 0-7 additionally pack W into fragment order:
// packed[((j*4+t)*64+l)*8+i] = bf16(W[j][(l>>4)*8+i][(l&15)+16t])
__global__ void scatter_pack(const int* __restrict__ out_idx,
                             const int* __restrict__ k_idx,
                             const float* __restrict__ W,
                             int* __restrict__ slot, int* __restrict__ next,
                             unsigned* __restrict__ cm_inv,
                             short* __restrict__ packed, int n)
{
    const int i = blockIdx.x * 256 + threadIdx.x;
    if (blockIdx.x < 8) {                       // W pack (2048 threads)
        const int s = i;
        const int j = s >> 8, t = (s >> 6) & 3, l = s & 63;
        const int k0 = (l >> 4) * 8, c = (l & 15) + 16 * t;
        short8 v;
#pragma unroll
        for (int q = 0; q < 8; ++q)
            v[q] = f2bf(W[(j * 32 + k0 + q) * 64 + c]);
        ((short8*)packed)[s] = v;
    }
    if (i < n) {
        const int o = out_idx[i];
        const int k = k_idx[i];
        int old = atomicExch(&slot[(size_t)o * 8 + k], i);
        next[i] = old;                          // chain walk needs -1 terminator
        if (old >= 0) atomicAnd(&cm_inv[o], ~(1u << k));   // rare (~2%)
    }
}

// ---------------------------------------------------------------------------
// MFMA gather: block = 8 waves x 16 outputs = 128 outputs. R4 structure.
// ---------------------------------------------------------------------------
__global__ __launch_bounds__(512, 8) void gather_mfma(
    const float* __restrict__ x, const short* __restrict__ packedW,
    const int* __restrict__ slot, const int* __restrict__ next_arr,
    const unsigned* __restrict__ cm_inv,
    float* __restrict__ out, float* __restrict__ partials,
    int num_out, int nb)
{
    __shared__ short sW[16384];          // 32 KB: [j][tile][lane][8]
    __shared__ float s_stat[128];

    const int tid = threadIdx.x;
    const int wave = tid >> 6, lane = tid & 63;
    const int quad = lane >> 4, row = lane & 15;
    const int obase = blockIdx.x * 128 + wave * 16;
    const int o = obase + row;
    const bool valid_o = (o < num_out);

    // Hoisted slot + chainmask loads: latency hides under W staging + barrier.
    int4 sl0 = make_int4(-1, -1, -1, -1), sl1 = sl0;
    unsigned cmraw = 0xFFFFFFFFu;        // inverted: bit==0 means chain present
    if (valid_o) {
        const int4* sp = (const int4*)(slot + (size_t)o * 8);
        sl0 = sp[0]; sl1 = sp[1];
        cmraw = cm_inv[o];
    }

    if (tid < 128) s_stat[tid] = 0.f;
    for (int i = tid; i < 2048; i += 512)
        ((short8*)sW)[i] = ((const short8*)packedW)[i];
    __syncthreads();

    const unsigned cm = ~cmraw;          // bit j set => duplicate chain at j

    floatx4 acc[4] = {{0,0,0,0},{0,0,0,0},{0,0,0,0},{0,0,0,0}};
    const short8* bw = (const short8*)sW;

#pragma unroll
    for (int j = 0; j < 8; ++j) {
        const int v = (j < 4) ? ((j == 0) ? sl0.x : (j == 1) ? sl0.y : (j == 2) ? sl0.z : sl0.w)
                              : ((j == 4) ? sl1.x : (j == 5) ? sl1.y : (j == 6) ? sl1.z : sl1.w);
        if (!__any(v >= 0)) continue;            // whole wave empty at this j
        float4 xa = make_float4(0.f, 0.f, 0.f, 0.f), xb = xa;
        if (v >= 0) {                            // exec-masked (empty lanes free)
            const float4* xp = (const float4*)(x + (size_t)v * 32) + quad * 2;
            xa = xp[0]; xb = xp[1];
        }
        if (__builtin_expect(__any((cm >> j) & 1u), 0)) {   // rare dup chain
            int w = (v >= 0 && ((cm >> j) & 1u)) ? next_arr[v] : -1;
            while (__any(w >= 0)) {
                if (w >= 0) {
                    const float4* xp2 = (const float4*)(x + (size_t)w * 32) + quad * 2;
                    float4 ya = xp2[0], yb = xp2[1];
                    xa.x += ya.x; xa.y += ya.y; xa.z += ya.z; xa.w += ya.w;
                    xb.x += yb.x; xb.y += yb.y; xb.z += yb.z; xb.w += yb.w;
                    w = next_arr[w];
                }
            }
        }
        short8 afrag;
        afrag[0] = f2bf(xa.x); afrag[1] = f2bf(xa.y);
        afrag[2] = f2bf(xa.z); afrag[3] = f2bf(xa.w);
        afrag[4] = f2bf(xb.x); afrag[5] = f2bf(xb.y);
        afrag[6] = f2bf(xb.z); afrag[7] = f2bf(xb.w);

        const int jb = j * 256;
#pragma unroll
        for (int t = 0; t < 4; ++t) {
            const short8 bfrag = bw[jb + t * 64 + lane];
            acc[t] = __builtin_amdgcn_mfma_f32_16x16x32_bf16(afrag, bfrag, acc[t], 0, 0, 0);
        }
    }

    // Epilogue: C layout col=lane&15, row=quad*4+reg. Store + fused stats.
#pragma unroll
    for (int t = 0; t < 4; ++t) {
        const int c = (lane & 15) + 16 * t;
        float sum = 0.f, sq = 0.f;
#pragma unroll
        for (int r = 0; r < 4; ++r) {
            const int oc = obase + quad * 4 + r;
            const float val = acc[t][r];
            if (oc < num_out) {
                out[(size_t)oc * 64 + c] = val;
                sum += val; sq += val * val;
            }
        }
        sum += __shfl_xor(sum, 16, 64); sum += __shfl_xor(sum, 32, 64);
        sq  += __shfl_xor(sq, 16, 64);  sq  += __shfl_xor(sq, 32, 64);
        if (quad == 0) {
            atomicAdd(&s_stat[c], sum);
            atomicAdd(&s_stat[64 + c], sq);
        }
    }
    __syncthreads();
    if (tid < 128) partials[(size_t)tid * nb + blockIdx.x] = s_stat[tid];
}

// One block per channel c: reduce partials, emit a[c], b[c].
// (conv bias cancels under BN: final = (acc-mean)*rsqrt(var)*gamma+beta)
__global__ __launch_bounds__(256) void reduce_finalize(
    const float* __restrict__ partials, const float* __restrict__ gamma,
    const float* __restrict__ beta, float* __restrict__ ws_ab,
    int nb, float inv_n)
{
    __shared__ float r1[256], r2[256];
    const int c = blockIdx.x, t = threadIdx.x;
    float s1 = 0.f, s2 = 0.f;
    for (int i = t; i < nb; i += 256) {
        s1 += partials[(size_t)c * nb + i];
        s2 += partials[(size_t)(c + 64) * nb + i];
    }
    r1[t] = s1; r2[t] = s2;
    __syncthreads();
    for (int d = 128; d > 0; d >>= 1) {
        if (t < d) { r1[t] += r1[t + d]; r2[t] += r2[t + d]; }
        __syncthreads();
    }
    if (t == 0) {
        const float mean = r1[0] * inv_n;
        const float var = r2[0] * inv_n - mean * mean;
        const float a = gamma[c] * rsqrtf(var + EPS_BN);
        ws_ab[c] = a;                        // a[64]
        ws_ab[64 + c] = beta[c] - mean * a;  // b[64]
    }
}

__global__ __launch_bounds__(256) void apply_kernel(
    float* __restrict__ out, const float* __restrict__ ws_ab, int n4)
{
    const int tid = blockIdx.x * 256 + threadIdx.x;
    const int stride = gridDim.x * 256;          // multiple of 16 -> cg fixed
    const int cg = tid & 15;
    const floatx4 a = ((const floatx4*)ws_ab)[cg];
    const floatx4 b = ((const floatx4*)(ws_ab + 64))[cg];
    floatx4* o4 = (floatx4*)out;
    for (int i = tid; i < n4; i += stride) {
        floatx4 v = o4[i];                       // regular load: y is L3-hot
        v.x = fmaxf(fmaf(v.x, a.x, b.x), 0.f);
        v.y = fmaxf(fmaf(v.y, a.y, b.y), 0.f);
        v.z = fmaxf(fmaf(v.z, a.z, b.z), 0.f);
        v.w = fmaxf(fmaf(v.w, a.w, b.w), 0.f);
        __builtin_nontemporal_store(v, o4 + i);  // out never re-read
    }
}

extern "C" void kernel_launch(void* const* d_in, const int* in_sizes, int n_in,
                              void* d_out, int out_size, void* d_ws, size_t ws_size,
                              hipStream_t stream)
{
    const float* x     = (const float*)d_in[0];
    const float* W     = (const float*)d_in[1];
    // d_in[2] = bias: cancels under BN, unused.
    const float* gamma = (const float*)d_in[3];
    const float* beta  = (const float*)d_in[4];
    const int* k_idx   = (const int*)d_in[5];
    const int* out_idx = (const int*)d_in[6];

    const int n_vox   = in_sizes[5];
    const int num_out = out_size / 64;
    const int nb      = (num_out + 127) / 128;   // gather blocks (128 outputs)
    float* out = (float*)d_out;

    char* p = (char*)d_ws;
    float* ws_ab    = (float*)(p + 512);                 // a[64], b[64]
    short* packedW  = (short*)(p + 1024);                // 32 KB
    float* partials = (float*)(p + 1024 + 32768);        // 128*nb f32
    char*  p2       = p + 1024 + 32768 + (size_t)128 * nb * 4;
    int*   slot     = (int*)p2;                          // num_out*8
    unsigned* cm_inv = (unsigned*)(slot + (size_t)num_out * 8);  // num_out
    int*   next     = (int*)(cm_inv + num_out);          // n_vox

    // ONE memset: slot (=-1) and cm_inv (=0xFFFFFFFF, inverted chainmask)
    (void)hipMemsetAsync(slot, 0xFF, (size_t)num_out * 9 * sizeof(int), stream);

    const int nsb = (n_vox + 255) / 256;                 // >= 8 always here
    scatter_pack  <<<nsb, 256, 0, stream>>>(out_idx, k_idx, W, slot, next, cm_inv, packedW, n_vox);
    gather_mfma   <<<nb, 512, 0, stream>>>(x, packedW, slot, next, cm_inv, out, partials, num_out, nb);
    reduce_finalize<<<64, 256, 0, stream>>>(partials, gamma, beta, ws_ab, nb, 1.0f / (float)num_out);
    apply_kernel  <<<4096, 256, 0, stream>>>(out, ws_ab, out_size / 4);
}